// Round 7
// baseline (431.056 us; speedup 1.0000x reference)
//
#include <hip/hip_runtime.h>
#include <stdint.h>

// ---------------------------------------------------------------------------
// CrossAttentionRope: x(16,256,768), ctx(16,4096,768) f32 -> out(16,256,768) f32
// R7: K-proj + V-proj + ctx-cvt fused into ONE kernel (kvproj_kernel):
//     512 thr / 8 waves, block = 128 rows x (128 K-cols || 128 V-cols),
//     A read as f32 + cvt_pk during staging, col-fast + XCD swizzle.
//     GEMM staging reverted to R5 reg-staged+swizzle (R6 gld_lds was -3%).
//     attn / twt / Q / O kernels verbatim R5.
// ---------------------------------------------------------------------------

typedef __bf16 bf16x8 __attribute__((ext_vector_type(8)));
typedef unsigned short u16x8 __attribute__((ext_vector_type(8)));
typedef unsigned short u16x4 __attribute__((ext_vector_type(4)));
typedef uint32_t u32x4 __attribute__((ext_vector_type(4)));
typedef float f32x4 __attribute__((ext_vector_type(4)));

#define DIMF 768
#define NHEAD 12
#define NKV 4096
#define NQ 256
#define NB 16

struct alignas(8) us4 { unsigned short x, y, z, w; };

__device__ __forceinline__ unsigned short f2bf(float x) {
  uint32_t u = __float_as_uint(x);
  u += 0x7fffu + ((u >> 16) & 1u);   // round-to-nearest-even
  return (unsigned short)(u >> 16);
}

__device__ __forceinline__ uint32_t cvtpk(float a, float b) {
  uint32_t r;
  asm("v_cvt_pk_bf16_f32 %0, %1, %2" : "=v"(r) : "v"(a), "v"(b));
  return r;
}

// ---------------- convert f32 -> bf16 (x only now) -------------------------
__global__ void cvt_kernel(const float* __restrict__ in, unsigned short* __restrict__ out, int n) {
  int stride = gridDim.x * blockDim.x * 4;
  for (int i = (blockIdx.x * blockDim.x + threadIdx.x) * 4; i < n; i += stride) {
    float4 v = *(const float4*)(in + i);
    us4 o{f2bf(v.x), f2bf(v.y), f2bf(v.z), f2bf(v.w)};
    *(us4*)(out + i) = o;
  }
}

// ---------------- weight transpose + cvt: Wt[n][k] = W[k][n] ---------------
__global__ void twt_kernel(const float* __restrict__ W0, const float* __restrict__ W1,
                           const float* __restrict__ W2, const float* __restrict__ W3,
                           unsigned short* __restrict__ O0, unsigned short* __restrict__ O1,
                           unsigned short* __restrict__ O2, unsigned short* __restrict__ O3) {
  const float* W; unsigned short* O;
  switch (blockIdx.z) {
    case 0: W = W0; O = O0; break;
    case 1: W = W1; O = O1; break;
    case 2: W = W2; O = O2; break;
    default: W = W3; O = O3; break;
  }
  __shared__ float t[32][33];
  int x0 = blockIdx.x * 32, y0 = blockIdx.y * 32;
  int tx = threadIdx.x, ty = threadIdx.y;
#pragma unroll
  for (int j = 0; j < 4; ++j)
    t[ty + 8 * j][tx] = W[(size_t)(y0 + ty + 8 * j) * DIMF + x0 + tx];
  __syncthreads();
#pragma unroll
  for (int j = 0; j < 4; ++j)
    O[(size_t)(x0 + ty + 8 * j) * DIMF + y0 + tx] = f2bf(t[tx][ty + 8 * j]);
}

// ---------------- fused K+V projection (+cvt, +rope) ------------------------
// grid 3072 (XCD-swizzled, col-fast): block -> rows [rowBase,+128) x col-group
// cg (128 K-cols AND 128 V-cols). 8 waves: wr=wid>>2 (row half), wc=wid&3
// (col quarter of the 256-wide [K||V] tile). A staged from ctx f32 w/ cvt_pk.
__launch_bounds__(512, 4)
__global__ void kvproj_kernel(const float* __restrict__ ctx,
                              const unsigned short* __restrict__ wkt,
                              const unsigned short* __restrict__ wvt,
                              unsigned short* __restrict__ Ko,
                              unsigned short* __restrict__ Vt,
                              const float* __restrict__ rope) {
  __shared__ unsigned short As[128 * 64];   // 16KB, chunk ^= row&7
  __shared__ unsigned short Bs[256 * 64];   // 32KB (rows 0-127 K, 128-255 V)
  const int t = threadIdx.x;
  const int lane = t & 63, wid = t >> 6;
  const int g = lane >> 4, lc = lane & 15;
  const int wr = wid >> 2, wc = wid & 3;

  const int bid = blockIdx.x;
  const int swz = (bid & 7) * 384 + (bid >> 3);   // 3072%8==0: bijective
  const int cg = swz % 6;
  const int rowBase = (swz / 6) * 128;
  const int colBase = cg * 128;

  const f32x4 z4 = {0.f, 0.f, 0.f, 0.f};
  f32x4 acc[4][4];
#pragma unroll
  for (int m = 0; m < 4; ++m)
#pragma unroll
    for (int n = 0; n < 4; ++n) acc[m][n] = z4;

  // A staging map: row = t>>2 (128), 16 f32 at k-offset (t&3)*16
  const int ar = t >> 2, ac = t & 3;
  // B staging map: row = t>>1 (256), 4 chunks of 8 bf16 at (t&1)*32
  const int br = t >> 1, bc = t & 1;
  const unsigned short* Bsrc = (br < 128)
      ? wkt + (size_t)(colBase + br) * DIMF
      : wvt + (size_t)(colBase + br - 128) * DIMF;

  f32x4 fa[4];
  u16x8 rb[4];

#define LOAD_STEP(KB)                                                          \
  do {                                                                         \
    const float* Ab = ctx + (size_t)(rowBase + ar) * DIMF + (KB) * 64 + ac * 16; \
    _Pragma("unroll")                                                          \
    for (int i = 0; i < 4; ++i) fa[i] = *(const f32x4*)(Ab + 4 * i);           \
    const unsigned short* Bb = Bsrc + (KB) * 64 + bc * 32;                     \
    _Pragma("unroll")                                                          \
    for (int i = 0; i < 4; ++i) rb[i] = *(const u16x8*)(Bb + 8 * i);           \
  } while (0)

  LOAD_STEP(0);

  for (int kb = 0; kb < 12; ++kb) {
    __syncthreads();   // previous K-step's ds_reads complete
    // A: convert 16 f32 -> 2 x 16B chunks, swizzled write
#pragma unroll
    for (int j = 0; j < 2; ++j) {
      u32x4 pw = {cvtpk(fa[2 * j][0], fa[2 * j][1]),
                  cvtpk(fa[2 * j][2], fa[2 * j][3]),
                  cvtpk(fa[2 * j + 1][0], fa[2 * j + 1][1]),
                  cvtpk(fa[2 * j + 1][2], fa[2 * j + 1][3])};
      int c = ac * 2 + j;
      *(u32x4*)&As[ar * 64 + ((c ^ (ar & 7)) << 3)] = pw;
    }
    // B: 4 swizzled 16B writes
#pragma unroll
    for (int i = 0; i < 4; ++i) {
      int c = bc * 4 + i;
      *(u16x8*)&Bs[br * 64 + ((c ^ (br & 7)) << 3)] = rb[i];
    }
    __syncthreads();
    if (kb + 1 < 12) LOAD_STEP(kb + 1);   // prefetch next K-step
#pragma unroll
    for (int kk = 0; kk < 2; ++kk) {
      bf16x8 af[4], bfr[4];
#pragma unroll
      for (int m = 0; m < 4; ++m) {
        int row = wr * 64 + m * 16 + lc;
        af[m] = *(const bf16x8*)&As[row * 64 + (((kk * 4 + g) ^ (row & 7)) << 3)];
      }
#pragma unroll
      for (int n = 0; n < 4; ++n) {
        int row = wc * 64 + n * 16 + lc;
        bfr[n] = *(const bf16x8*)&Bs[row * 64 + (((kk * 4 + g) ^ (row & 7)) << 3)];
      }
#pragma unroll
      for (int m = 0; m < 4; ++m)
#pragma unroll
        for (int n = 0; n < 4; ++n)
          acc[m][n] = __builtin_amdgcn_mfma_f32_16x16x32_bf16(af[m], bfr[n], acc[m][n], 0, 0, 0);
    }
  }
#undef LOAD_STEP

  // ---- epilogue (C/D: col=lc, row=g*4+r — verified) ----
  if (wc < 2) {   // K output + rope
#pragma unroll
    for (int m = 0; m < 4; ++m)
#pragma unroll
      for (int n = 0; n < 4; ++n)
#pragma unroll
        for (int r = 0; r < 4; ++r) {
          int p = rowBase + wr * 64 + m * 16 + g * 4 + r;
          int f = colBase + wc * 64 + n * 16 + lc;
          int d = f & 63, h = f >> 6;
          float v = acc[m][n][r];
          float vo = __shfl_xor(v, 1);
          int b = p >> 12, nkv = p & 4095;
          float sn = rope[nkv * 128 + d], cs = rope[nkv * 128 + 64 + d];
          float o = (d & 1) ? fmaf(vo, sn, v * cs) : fmaf(-vo, sn, v * cs);
          Ko[((size_t)(b * NHEAD + h) * NKV + nkv) * 64 + d] = f2bf(o);
        }
  } else {        // V output, transposed [b][h][d][nkv]
#pragma unroll
    for (int m = 0; m < 4; ++m)
#pragma unroll
      for (int n = 0; n < 4; ++n) {
        int p0 = rowBase + wr * 64 + m * 16 + g * 4;
        int b = p0 >> 12, nkv0 = p0 & 4095;
        int f = colBase + (wc - 2) * 64 + n * 16 + lc;
        int d = f & 63, h = f >> 6;
        us4 wv{f2bf(acc[m][n][0]), f2bf(acc[m][n][1]), f2bf(acc[m][n][2]), f2bf(acc[m][n][3])};
        *(us4*)&Vt[((size_t)(b * NHEAD + h) * 64 + d) * NKV + nkv0] = wv;
      }
  }
}

// ---------------- GEMM (R5-proven reg-staged): Q-proj / O-proj --------------
// MODE 2: Q-proj (+rope_q, *0.125) -> Q [b][h][nq][64] bf16
// MODE 3: O-proj -> out f32 [p][768]
template <int MODE>
__launch_bounds__(256, 2)
__global__ void gemm_kernel(const unsigned short* __restrict__ A,
                            const unsigned short* __restrict__ Bt,
                            void* __restrict__ outp,
                            const float* __restrict__ rope) {
  __shared__ unsigned short As[128 * 64];
  __shared__ unsigned short Bs[128 * 64];
  const int t = threadIdx.x;
  const int lane = t & 63, wid = t >> 6;
  const int g = lane >> 4, lc = lane & 15;
  const int wr = wid >> 1, wc = wid & 1;
  const int rowBase = blockIdx.x * 128, colBase = blockIdx.y * 128;

  const f32x4 z4 = {0.f, 0.f, 0.f, 0.f};
  f32x4 acc[4][4];
#pragma unroll
  for (int m = 0; m < 4; ++m)
#pragma unroll
    for (int n = 0; n < 4; ++n) acc[m][n] = z4;

  const int r0 = t >> 3;
  const int c0 = t & 7;

  bf16x8 ra[4], rbx[4];
#pragma unroll
  for (int pp = 0; pp < 4; ++pp) {
    int row = pp * 32 + r0;
    ra[pp] = *(const bf16x8*)(A + (size_t)(rowBase + row) * DIMF + c0 * 8);
    rbx[pp] = *(const bf16x8*)(Bt + (size_t)(colBase + row) * DIMF + c0 * 8);
  }

  for (int kb = 0; kb < 12; ++kb) {
    __syncthreads();
#pragma unroll
    for (int pp = 0; pp < 4; ++pp) {
      int row = pp * 32 + r0;
      int ph = ((c0 ^ (row & 7)) << 3);
      *(bf16x8*)&As[row * 64 + ph] = ra[pp];
      *(bf16x8*)&Bs[row * 64 + ph] = rbx[pp];
    }
    __syncthreads();
    if (kb + 1 < 12) {
      int kn = (kb + 1) * 64;
#pragma unroll
      for (int pp = 0; pp < 4; ++pp) {
        int row = pp * 32 + r0;
        ra[pp] = *(const bf16x8*)(A + (size_t)(rowBase + row) * DIMF + kn + c0 * 8);
        rbx[pp] = *(const bf16x8*)(Bt + (size_t)(colBase + row) * DIMF + kn + c0 * 8);
      }
    }
#pragma unroll
    for (int kk = 0; kk < 2; ++kk) {
      bf16x8 af[4], bfr[4];
#pragma unroll
      for (int m = 0; m < 4; ++m) {
        int row = wr * 64 + m * 16 + lc;
        int ch = kk * 4 + g;
        af[m] = *(const bf16x8*)&As[row * 64 + (((ch ^ (row & 7))) << 3)];
      }
#pragma unroll
      for (int n = 0; n < 4; ++n) {
        int row = wc * 64 + n * 16 + lc;
        int ch = kk * 4 + g;
        bfr[n] = *(const bf16x8*)&Bs[row * 64 + (((ch ^ (row & 7))) << 3)];
      }
#pragma unroll
      for (int m = 0; m < 4; ++m)
#pragma unroll
        for (int n = 0; n < 4; ++n)
          acc[m][n] = __builtin_amdgcn_mfma_f32_16x16x32_bf16(af[m], bfr[n], acc[m][n], 0, 0, 0);
    }
  }

  if (MODE == 2) {
    unsigned short* Ko = (unsigned short*)outp;
#pragma unroll
    for (int m = 0; m < 4; ++m)
#pragma unroll
      for (int n = 0; n < 4; ++n)
#pragma unroll
        for (int r = 0; r < 4; ++r) {
          int p = rowBase + wr * 64 + m * 16 + g * 4 + r;
          int f = colBase + wc * 64 + n * 16 + lc;
          int d = f & 63, h = f >> 6;
          float v = acc[m][n][r];
          float vo = __shfl_xor(v, 1);
          int b = p >> 8, nq = p & 255;
          float sn = rope[nq * 128 + d], cs = rope[nq * 128 + 64 + d];
          float o = (d & 1) ? fmaf(vo, sn, v * cs) : fmaf(-vo, sn, v * cs);
          Ko[((size_t)(b * NHEAD + h) * NQ + nq) * 64 + d] = f2bf(o * 0.125f);
        }
  } else {
    float* Co = (float*)outp;
#pragma unroll
    for (int m = 0; m < 4; ++m)
#pragma unroll
      for (int n = 0; n < 4; ++n)
#pragma unroll
        for (int r = 0; r < 4; ++r) {
          int p = rowBase + wr * 64 + m * 16 + g * 4 + r;
          int f = colBase + wc * 64 + n * 16 + lc;
          Co[(size_t)p * DIMF + f] = acc[m][n][r];
        }
  }
}

// ---------------- flash attention (R5-proven, verbatim) --------------------
__launch_bounds__(256, 2)
__global__ void attn_kernel(const unsigned short* __restrict__ Qb,
                            const unsigned short* __restrict__ Kb,
                            const unsigned short* __restrict__ Vtb,
                            unsigned short* __restrict__ Ob) {
  __shared__ unsigned short Ks[128 * 64];    // [kv][d]  16KB, chunk ^= (kv&7)
  __shared__ unsigned short Vts[64 * 128];   // [d][kv'] 16KB, chunk ^= (d&15)
  const int logical = (blockIdx.x & 7) * 96 + (blockIdx.x >> 3);  // 768%8==0
  const int qt = logical & 3, bh = logical >> 2;
  const int b = bh / NHEAD, h = bh % NHEAD;
  const int t = threadIdx.x;
  const int lane = t & 63, w = t >> 6;
  const int g = lane >> 4, lc = lane & 15;
  const int qrow = qt * 64 + w * 16 + lc;

  bf16x8 qf[2];
#pragma unroll
  for (int kk = 0; kk < 2; ++kk)
    qf[kk] = *(const bf16x8*)(Qb + ((size_t)bh * NQ + qrow) * 64 + kk * 32 + g * 8);

  const f32x4 z4 = {0.f, 0.f, 0.f, 0.f};
  f32x4 oacc[4];
#pragma unroll
  for (int df = 0; df < 4; ++df) oacc[df] = z4;
  float mrun = -1e30f, lrun = 0.f;

  const int r0 = t >> 3, c0 = t & 7;
  const int d0 = t >> 4, cv = t & 15;
  const int pbase = 32 * (cv >> 2) + 16 * (cv & 1) + 4 * ((cv >> 1) & 1);
  const int ch0 = pbase >> 3, of0 = pbase & 7;
  const int ch1 = (pbase + 8) >> 3;

  u16x8 rk[4], rv[4];
#define LOAD_TILE(KT)                                                                        \
  do {                                                                                       \
    const int kvb = (KT) * 128;                                                              \
    _Pragma("unroll")                                                                        \
    for (int pp = 0; pp < 4; ++pp)                                                           \
      rk[pp] = *(const u16x8*)(Kb + ((size_t)bh * NKV + kvb + pp * 32 + r0) * 64 + c0 * 8);  \
    _Pragma("unroll")                                                                        \
    for (int pp = 0; pp < 4; ++pp)                                                           \
      rv[pp] = *(const u16x8*)(Vtb + ((size_t)bh * 64 + pp * 16 + d0) * NKV + kvb + cv * 8); \
  } while (0)

  LOAD_TILE(0);

  for (int kt = 0; kt < 32; ++kt) {
    __syncthreads();
#pragma unroll
    for (int pp = 0; pp < 4; ++pp) {
      int row = pp * 32 + r0;
      *(u16x8*)&Ks[row * 64 + ((c0 ^ (row & 7)) << 3)] = rk[pp];
    }
#pragma unroll
    for (int pp = 0; pp < 4; ++pp) {
      int d = pp * 16 + d0;
      u16x4 lo = __builtin_shufflevector(rv[pp], rv[pp], 0, 1, 2, 3);
      u16x4 hi = __builtin_shufflevector(rv[pp], rv[pp], 4, 5, 6, 7);
      *(u16x4*)&Vts[d * 128 + ((ch0 ^ (d & 15)) << 3) + of0] = lo;
      *(u16x4*)&Vts[d * 128 + ((ch1 ^ (d & 15)) << 3) + of0] = hi;
    }
    if (kt + 1 < 32) LOAD_TILE(kt + 1);
    __syncthreads();

    f32x4 s[8];
#pragma unroll
    for (int c = 0; c < 8; ++c) s[c] = z4;
#pragma unroll
    for (int kk = 0; kk < 2; ++kk)
#pragma unroll
      for (int c = 0; c < 8; ++c) {
        int row = c * 16 + lc;
        bf16x8 kf = *(const bf16x8*)&Ks[row * 64 + (((kk * 4 + g) ^ (row & 7)) << 3)];
        s[c] = __builtin_amdgcn_mfma_f32_16x16x32_bf16(kf, qf[kk], s[c], 0, 0, 0);
      }

    float mx = s[0][0];
#pragma unroll
    for (int c = 0; c < 8; ++c)
#pragma unroll
      for (int r = 0; r < 4; ++r) mx = fmaxf(mx, s[c][r]);
    mx = fmaxf(mx, __shfl_xor(mx, 16));
    mx = fmaxf(mx, __shfl_xor(mx, 32));
    float nm = fmaxf(mrun, mx);
    float al = __expf(mrun - nm);
    mrun = nm;
    float ls = 0.f;
#pragma unroll
    for (int c = 0; c < 8; ++c)
#pragma unroll
      for (int r = 0; r < 4; ++r) {
        float p = __expf(s[c][r] - nm);
        s[c][r] = p;
        ls += p;
      }
    ls += __shfl_xor(ls, 16);
    ls += __shfl_xor(ls, 32);
    lrun = lrun * al + ls;
#pragma unroll
    for (int df = 0; df < 4; ++df)
#pragma unroll
      for (int r = 0; r < 4; ++r) oacc[df][r] *= al;

    uint32_t pk[8][2];
#pragma unroll
    for (int c = 0; c < 8; ++c)
#pragma unroll
      for (int w2 = 0; w2 < 2; ++w2)
        pk[c][w2] = cvtpk(s[c][2 * w2], s[c][2 * w2 + 1]);

#pragma unroll
    for (int kb = 0; kb < 4; ++kb) {
      u32x4 pw = {pk[2 * kb][0], pk[2 * kb][1], pk[2 * kb + 1][0], pk[2 * kb + 1][1]};
      bf16x8 pa = __builtin_bit_cast(bf16x8, pw);
#pragma unroll
      for (int df = 0; df < 4; ++df) {
        int row = df * 16 + lc;
        bf16x8 vf = *(const bf16x8*)&Vts[row * 128 + (((kb * 4 + g) ^ (row & 15)) << 3)];
        oacc[df] = __builtin_amdgcn_mfma_f32_16x16x32_bf16(vf, pa, oacc[df], 0, 0, 0);
      }
    }
  }
#undef LOAD_TILE

  float inv = 1.0f / lrun;
#pragma unroll
  for (int df = 0; df < 4; ++df) {
    us4 wv{f2bf(oacc[df][0] * inv), f2bf(oacc[df][1] * inv),
           f2bf(oacc[df][2] * inv), f2bf(oacc[df][3] * inv)};
    *(us4*)&Ob[((size_t)b * NQ + qrow) * DIMF + h * 64 + df * 16 + g * 4] = wv;
  }
}

// ---------------- launch ----------------------------------------------------
extern "C" void kernel_launch(void* const* d_in, const int* in_sizes, int n_in,
                              void* d_out, int out_size, void* d_ws, size_t ws_size,
                              hipStream_t stream) {
  const float* x      = (const float*)d_in[0];
  const float* ctx    = (const float*)d_in[1];
  const float* rope_q = (const float*)d_in[2];
  const float* rope_k = (const float*)d_in[3];
  const float* Wq     = (const float*)d_in[4];
  const float* Wk     = (const float*)d_in[5];
  const float* Wv     = (const float*)d_in[6];
  const float* Wo     = (const float*)d_in[7];

  char* ws = (char*)d_ws;
  const size_t SZ_CTXB = (size_t)NB * NKV * DIMF * 2;
  const size_t SZ_XB   = (size_t)NB * NQ * DIMF * 2;
  const size_t SZ_WT   = (size_t)DIMF * DIMF * 2;
  unsigned short* ob   = (unsigned short*)(ws);                       // (ctxb slot reused)
  unsigned short* xb   = (unsigned short*)(ws + SZ_CTXB);
  unsigned short* wkt  = (unsigned short*)(ws + SZ_CTXB + SZ_XB);
  unsigned short* wvt  = (unsigned short*)(ws + SZ_CTXB + SZ_XB + SZ_WT);
  unsigned short* wqt  = (unsigned short*)(ws + SZ_CTXB + SZ_XB + 2 * SZ_WT);
  unsigned short* wot  = (unsigned short*)(ws + SZ_CTXB + SZ_XB + 3 * SZ_WT);
  unsigned short* kb   = (unsigned short*)(ws + SZ_CTXB + SZ_XB + 4 * SZ_WT);
  unsigned short* vtb  = (unsigned short*)(ws + SZ_CTXB + SZ_XB + 4 * SZ_WT + SZ_CTXB);
  unsigned short* qb   = (unsigned short*)(ws + SZ_CTXB + SZ_XB + 4 * SZ_WT + 2 * SZ_CTXB);

  cvt_kernel<<<dim3(1024), dim3(256), 0, stream>>>(x, xb, NB * NQ * DIMF);
  twt_kernel<<<dim3(24, 24, 4), dim3(32, 8), 0, stream>>>(Wk, Wv, Wq, Wo, wkt, wvt, wqt, wot);

  kvproj_kernel<<<dim3(3072), dim3(512), 0, stream>>>(ctx, wkt, wvt, kb, vtb, rope_k);
  gemm_kernel<2><<<dim3(32, 6), dim3(256), 0, stream>>>(xb, wqt, qb, rope_q);

  attn_kernel<<<dim3(768), dim3(256), 0, stream>>>(qb, kb, vtb, ob);

  gemm_kernel<3><<<dim3(32, 6), dim3(256), 0, stream>>>(ob, wot, d_out, nullptr);
}

// Round 8
// 393.994 us; speedup vs baseline: 1.0941x; 1.0941x over previous
//
#include <hip/hip_runtime.h>
#include <stdint.h>

// ---------------------------------------------------------------------------
// CrossAttentionRope: x(16,256,768), ctx(16,4096,768) f32 -> out(16,256,768) f32
// R8: full revert to R5 (best: 409us) + ONE change: KV GEMMs get col-fast +
//     XCD-bijective block swizzle (T1) — A-panel's 6 col-blocks adjacent on
//     one XCD -> staging hits local L2, shortening the latency-bound
//     stage/barrier critical path. Everything else verbatim R5.
// ---------------------------------------------------------------------------

typedef __bf16 bf16x8 __attribute__((ext_vector_type(8)));
typedef unsigned short u16x8 __attribute__((ext_vector_type(8)));
typedef unsigned short u16x4 __attribute__((ext_vector_type(4)));
typedef uint32_t u32x4 __attribute__((ext_vector_type(4)));
typedef float f32x4 __attribute__((ext_vector_type(4)));

#define DIMF 768
#define NHEAD 12
#define NKV 4096
#define NQ 256
#define NB 16

struct alignas(8) us4 { unsigned short x, y, z, w; };

__device__ __forceinline__ unsigned short f2bf(float x) {
  uint32_t u = __float_as_uint(x);
  u += 0x7fffu + ((u >> 16) & 1u);   // round-to-nearest-even
  return (unsigned short)(u >> 16);
}

__device__ __forceinline__ uint32_t cvtpk(float a, float b) {
  uint32_t r;
  asm("v_cvt_pk_bf16_f32 %0, %1, %2" : "=v"(r) : "v"(a), "v"(b));
  return r;
}

// ---------------- convert f32 -> bf16 (vectorized, grid-stride) ------------
__global__ void cvt_kernel(const float* __restrict__ in, unsigned short* __restrict__ out, int n) {
  int stride = gridDim.x * blockDim.x * 4;
  for (int i = (blockIdx.x * blockDim.x + threadIdx.x) * 4; i < n; i += stride) {
    float4 v = *(const float4*)(in + i);
    us4 o{f2bf(v.x), f2bf(v.y), f2bf(v.z), f2bf(v.w)};
    *(us4*)(out + i) = o;
  }
}

// ---------------- weight transpose + cvt: Wt[n][k] = W[k][n] ---------------
__global__ void twt_kernel(const float* __restrict__ W0, const float* __restrict__ W1,
                           const float* __restrict__ W2, const float* __restrict__ W3,
                           unsigned short* __restrict__ O0, unsigned short* __restrict__ O1,
                           unsigned short* __restrict__ O2, unsigned short* __restrict__ O3) {
  const float* W; unsigned short* O;
  switch (blockIdx.z) {
    case 0: W = W0; O = O0; break;
    case 1: W = W1; O = O1; break;
    case 2: W = W2; O = O2; break;
    default: W = W3; O = O3; break;
  }
  __shared__ float t[32][33];
  int x0 = blockIdx.x * 32, y0 = blockIdx.y * 32;
  int tx = threadIdx.x, ty = threadIdx.y;
#pragma unroll
  for (int j = 0; j < 4; ++j)
    t[ty + 8 * j][tx] = W[(size_t)(y0 + ty + 8 * j) * DIMF + x0 + tx];
  __syncthreads();
#pragma unroll
  for (int j = 0; j < 4; ++j)
    O[(size_t)(x0 + ty + 8 * j) * DIMF + y0 + tx] = f2bf(t[tx][ty + 8 * j]);
}

// ---------------- GEMM (R5-proven reg-staged): C(128x128) = A * Bt^T --------
// MODE 0: K-proj (+rope_k)  -> K  [b][h][n][64]    bf16   [1D grid, XCD swz]
// MODE 1: V-proj            -> Vt [b][h][64][4096] bf16   [1D grid, XCD swz]
// MODE 2: Q-proj (+rope_q, *0.125) -> Q [b][h][nq][64] bf16  [2D grid]
// MODE 3: O-proj            -> out f32 [p][768]               [2D grid]
template <int MODE>
__launch_bounds__(256, 2)
__global__ void gemm_kernel(const unsigned short* __restrict__ A,
                            const unsigned short* __restrict__ Bt,
                            void* __restrict__ outp,
                            const float* __restrict__ rope) {
  __shared__ unsigned short As[128 * 64];
  __shared__ unsigned short Bs[128 * 64];
  const int t = threadIdx.x;
  const int lane = t & 63, wid = t >> 6;
  const int g = lane >> 4, lc = lane & 15;
  const int wr = wid >> 1, wc = wid & 1;

  int rowBase, colBase;
  if (MODE == 0 || MODE == 1) {
    // 3072 blocks, 3072%8==0: bijective XCD remap; col (swz%6) fast so the
    // 6 col-blocks sharing one A row-panel are adjacent on the same XCD.
    const int swz = (blockIdx.x & 7) * 384 + (blockIdx.x >> 3);
    rowBase = (swz / 6) * 128;
    colBase = (swz % 6) * 128;
  } else {
    rowBase = blockIdx.x * 128;
    colBase = blockIdx.y * 128;
  }

  const f32x4 z4 = {0.f, 0.f, 0.f, 0.f};
  f32x4 acc[4][4];
#pragma unroll
  for (int m = 0; m < 4; ++m)
#pragma unroll
    for (int n = 0; n < 4; ++n) acc[m][n] = z4;

  const int r0 = t >> 3;
  const int c0 = t & 7;

  bf16x8 ra[4], rbx[4];
#pragma unroll
  for (int pp = 0; pp < 4; ++pp) {
    int row = pp * 32 + r0;
    ra[pp] = *(const bf16x8*)(A + (size_t)(rowBase + row) * DIMF + c0 * 8);
    rbx[pp] = *(const bf16x8*)(Bt + (size_t)(colBase + row) * DIMF + c0 * 8);
  }

  for (int kb = 0; kb < 12; ++kb) {
    __syncthreads();
#pragma unroll
    for (int pp = 0; pp < 4; ++pp) {
      int row = pp * 32 + r0;
      int ph = ((c0 ^ (row & 7)) << 3);
      *(bf16x8*)&As[row * 64 + ph] = ra[pp];
      *(bf16x8*)&Bs[row * 64 + ph] = rbx[pp];
    }
    __syncthreads();
    if (kb + 1 < 12) {
      int kn = (kb + 1) * 64;
#pragma unroll
      for (int pp = 0; pp < 4; ++pp) {
        int row = pp * 32 + r0;
        ra[pp] = *(const bf16x8*)(A + (size_t)(rowBase + row) * DIMF + kn + c0 * 8);
        rbx[pp] = *(const bf16x8*)(Bt + (size_t)(colBase + row) * DIMF + kn + c0 * 8);
      }
    }
#pragma unroll
    for (int kk = 0; kk < 2; ++kk) {
      bf16x8 af[4], bfr[4];
#pragma unroll
      for (int m = 0; m < 4; ++m) {
        int row = wr * 64 + m * 16 + lc;
        int ch = kk * 4 + g;
        af[m] = *(const bf16x8*)&As[row * 64 + (((ch ^ (row & 7))) << 3)];
      }
#pragma unroll
      for (int n = 0; n < 4; ++n) {
        int row = wc * 64 + n * 16 + lc;
        int ch = kk * 4 + g;
        bfr[n] = *(const bf16x8*)&Bs[row * 64 + (((ch ^ (row & 7))) << 3)];
      }
#pragma unroll
      for (int m = 0; m < 4; ++m)
#pragma unroll
        for (int n = 0; n < 4; ++n)
          acc[m][n] = __builtin_amdgcn_mfma_f32_16x16x32_bf16(af[m], bfr[n], acc[m][n], 0, 0, 0);
    }
  }

  if (MODE == 0 || MODE == 2) {
    unsigned short* Ko = (unsigned short*)outp;
#pragma unroll
    for (int m = 0; m < 4; ++m)
#pragma unroll
      for (int n = 0; n < 4; ++n)
#pragma unroll
        for (int r = 0; r < 4; ++r) {
          int p = rowBase + wr * 64 + m * 16 + g * 4 + r;
          int f = colBase + wc * 64 + n * 16 + lc;
          int d = f & 63, h = f >> 6;
          float v = acc[m][n][r];
          float vo = __shfl_xor(v, 1);
          if (MODE == 0) {
            int b = p >> 12, nkv = p & 4095;
            float sn = rope[nkv * 128 + d], cs = rope[nkv * 128 + 64 + d];
            float o = (d & 1) ? fmaf(vo, sn, v * cs) : fmaf(-vo, sn, v * cs);
            Ko[((size_t)(b * NHEAD + h) * NKV + nkv) * 64 + d] = f2bf(o);
          } else {
            int b = p >> 8, nq = p & 255;
            float sn = rope[nq * 128 + d], cs = rope[nq * 128 + 64 + d];
            float o = (d & 1) ? fmaf(vo, sn, v * cs) : fmaf(-vo, sn, v * cs);
            Ko[((size_t)(b * NHEAD + h) * NQ + nq) * 64 + d] = f2bf(o * 0.125f);
          }
        }
  } else if (MODE == 1) {
    unsigned short* Vt = (unsigned short*)outp;
#pragma unroll
    for (int m = 0; m < 4; ++m)
#pragma unroll
      for (int n = 0; n < 4; ++n) {
        int p0 = rowBase + wr * 64 + m * 16 + g * 4;
        int b = p0 >> 12, nkv0 = p0 & 4095;
        int f = colBase + wc * 64 + n * 16 + lc;
        int d = f & 63, h = f >> 6;
        us4 wv{f2bf(acc[m][n][0]), f2bf(acc[m][n][1]), f2bf(acc[m][n][2]), f2bf(acc[m][n][3])};
        *(us4*)&Vt[((size_t)(b * NHEAD + h) * 64 + d) * NKV + nkv0] = wv;
      }
  } else {
    float* Co = (float*)outp;
#pragma unroll
    for (int m = 0; m < 4; ++m)
#pragma unroll
      for (int n = 0; n < 4; ++n)
#pragma unroll
        for (int r = 0; r < 4; ++r) {
          int p = rowBase + wr * 64 + m * 16 + g * 4 + r;
          int f = colBase + wc * 64 + n * 16 + lc;
          Co[(size_t)p * DIMF + f] = acc[m][n][r];
        }
  }
}

// ---------------- flash attention (R5-proven, verbatim) --------------------
__launch_bounds__(256, 2)
__global__ void attn_kernel(const unsigned short* __restrict__ Qb,
                            const unsigned short* __restrict__ Kb,
                            const unsigned short* __restrict__ Vtb,
                            unsigned short* __restrict__ Ob) {
  __shared__ unsigned short Ks[128 * 64];    // [kv][d]  16KB, chunk ^= (kv&7)
  __shared__ unsigned short Vts[64 * 128];   // [d][kv'] 16KB, chunk ^= (d&15)
  const int logical = (blockIdx.x & 7) * 96 + (blockIdx.x >> 3);  // 768%8==0
  const int qt = logical & 3, bh = logical >> 2;
  const int b = bh / NHEAD, h = bh % NHEAD;
  const int t = threadIdx.x;
  const int lane = t & 63, w = t >> 6;
  const int g = lane >> 4, lc = lane & 15;
  const int qrow = qt * 64 + w * 16 + lc;

  bf16x8 qf[2];
#pragma unroll
  for (int kk = 0; kk < 2; ++kk)
    qf[kk] = *(const bf16x8*)(Qb + ((size_t)bh * NQ + qrow) * 64 + kk * 32 + g * 8);

  const f32x4 z4 = {0.f, 0.f, 0.f, 0.f};
  f32x4 oacc[4];
#pragma unroll
  for (int df = 0; df < 4; ++df) oacc[df] = z4;
  float mrun = -1e30f, lrun = 0.f;

  const int r0 = t >> 3, c0 = t & 7;
  const int d0 = t >> 4, cv = t & 15;
  const int pbase = 32 * (cv >> 2) + 16 * (cv & 1) + 4 * ((cv >> 1) & 1);
  const int ch0 = pbase >> 3, of0 = pbase & 7;
  const int ch1 = (pbase + 8) >> 3;

  u16x8 rk[4], rv[4];
#define LOAD_TILE(KT)                                                                        \
  do {                                                                                       \
    const int kvb = (KT) * 128;                                                              \
    _Pragma("unroll")                                                                        \
    for (int pp = 0; pp < 4; ++pp)                                                           \
      rk[pp] = *(const u16x8*)(Kb + ((size_t)bh * NKV + kvb + pp * 32 + r0) * 64 + c0 * 8);  \
    _Pragma("unroll")                                                                        \
    for (int pp = 0; pp < 4; ++pp)                                                           \
      rv[pp] = *(const u16x8*)(Vtb + ((size_t)bh * 64 + pp * 16 + d0) * NKV + kvb + cv * 8); \
  } while (0)

  LOAD_TILE(0);

  for (int kt = 0; kt < 32; ++kt) {
    __syncthreads();
#pragma unroll
    for (int pp = 0; pp < 4; ++pp) {
      int row = pp * 32 + r0;
      *(u16x8*)&Ks[row * 64 + ((c0 ^ (row & 7)) << 3)] = rk[pp];
    }
#pragma unroll
    for (int pp = 0; pp < 4; ++pp) {
      int d = pp * 16 + d0;
      u16x4 lo = __builtin_shufflevector(rv[pp], rv[pp], 0, 1, 2, 3);
      u16x4 hi = __builtin_shufflevector(rv[pp], rv[pp], 4, 5, 6, 7);
      *(u16x4*)&Vts[d * 128 + ((ch0 ^ (d & 15)) << 3) + of0] = lo;
      *(u16x4*)&Vts[d * 128 + ((ch1 ^ (d & 15)) << 3) + of0] = hi;
    }
    if (kt + 1 < 32) LOAD_TILE(kt + 1);
    __syncthreads();

    f32x4 s[8];
#pragma unroll
    for (int c = 0; c < 8; ++c) s[c] = z4;
#pragma unroll
    for (int kk = 0; kk < 2; ++kk)
#pragma unroll
      for (int c = 0; c < 8; ++c) {
        int row = c * 16 + lc;
        bf16x8 kf = *(const bf16x8*)&Ks[row * 64 + (((kk * 4 + g) ^ (row & 7)) << 3)];
        s[c] = __builtin_amdgcn_mfma_f32_16x16x32_bf16(kf, qf[kk], s[c], 0, 0, 0);
      }

    float mx = s[0][0];
#pragma unroll
    for (int c = 0; c < 8; ++c)
#pragma unroll
      for (int r = 0; r < 4; ++r) mx = fmaxf(mx, s[c][r]);
    mx = fmaxf(mx, __shfl_xor(mx, 16));
    mx = fmaxf(mx, __shfl_xor(mx, 32));
    float nm = fmaxf(mrun, mx);
    float al = __expf(mrun - nm);
    mrun = nm;
    float ls = 0.f;
#pragma unroll
    for (int c = 0; c < 8; ++c)
#pragma unroll
      for (int r = 0; r < 4; ++r) {
        float p = __expf(s[c][r] - nm);
        s[c][r] = p;
        ls += p;
      }
    ls += __shfl_xor(ls, 16);
    ls += __shfl_xor(ls, 32);
    lrun = lrun * al + ls;
#pragma unroll
    for (int df = 0; df < 4; ++df)
#pragma unroll
      for (int r = 0; r < 4; ++r) oacc[df][r] *= al;

    uint32_t pk[8][2];
#pragma unroll
    for (int c = 0; c < 8; ++c)
#pragma unroll
      for (int w2 = 0; w2 < 2; ++w2)
        pk[c][w2] = cvtpk(s[c][2 * w2], s[c][2 * w2 + 1]);

#pragma unroll
    for (int kb = 0; kb < 4; ++kb) {
      u32x4 pw = {pk[2 * kb][0], pk[2 * kb][1], pk[2 * kb + 1][0], pk[2 * kb + 1][1]};
      bf16x8 pa = __builtin_bit_cast(bf16x8, pw);
#pragma unroll
      for (int df = 0; df < 4; ++df) {
        int row = df * 16 + lc;
        bf16x8 vf = *(const bf16x8*)&Vts[row * 128 + (((kb * 4 + g) ^ (row & 15)) << 3)];
        oacc[df] = __builtin_amdgcn_mfma_f32_16x16x32_bf16(vf, pa, oacc[df], 0, 0, 0);
      }
    }
  }
#undef LOAD_TILE

  float inv = 1.0f / lrun;
#pragma unroll
  for (int df = 0; df < 4; ++df) {
    us4 wv{f2bf(oacc[df][0] * inv), f2bf(oacc[df][1] * inv),
           f2bf(oacc[df][2] * inv), f2bf(oacc[df][3] * inv)};
    *(us4*)&Ob[((size_t)b * NQ + qrow) * DIMF + h * 64 + df * 16 + g * 4] = wv;
  }
}

// ---------------- launch ----------------------------------------------------
extern "C" void kernel_launch(void* const* d_in, const int* in_sizes, int n_in,
                              void* d_out, int out_size, void* d_ws, size_t ws_size,
                              hipStream_t stream) {
  const float* x      = (const float*)d_in[0];
  const float* ctx    = (const float*)d_in[1];
  const float* rope_q = (const float*)d_in[2];
  const float* rope_k = (const float*)d_in[3];
  const float* Wq     = (const float*)d_in[4];
  const float* Wk     = (const float*)d_in[5];
  const float* Wv     = (const float*)d_in[6];
  const float* Wo     = (const float*)d_in[7];

  char* ws = (char*)d_ws;
  const size_t SZ_CTXB = (size_t)NB * NKV * DIMF * 2;
  const size_t SZ_XB   = (size_t)NB * NQ * DIMF * 2;
  const size_t SZ_WT   = (size_t)DIMF * DIMF * 2;
  unsigned short* ctxb = (unsigned short*)(ws);
  unsigned short* ob   = (unsigned short*)(ws);                       // alias ctxb (dead after V-GEMM)
  unsigned short* xb   = (unsigned short*)(ws + SZ_CTXB);
  unsigned short* wkt  = (unsigned short*)(ws + SZ_CTXB + SZ_XB);
  unsigned short* wvt  = (unsigned short*)(ws + SZ_CTXB + SZ_XB + SZ_WT);
  unsigned short* wqt  = (unsigned short*)(ws + SZ_CTXB + SZ_XB + 2 * SZ_WT);
  unsigned short* wot  = (unsigned short*)(ws + SZ_CTXB + SZ_XB + 3 * SZ_WT);
  unsigned short* kb   = (unsigned short*)(ws + SZ_CTXB + SZ_XB + 4 * SZ_WT);
  unsigned short* vtb  = (unsigned short*)(ws + SZ_CTXB + SZ_XB + 4 * SZ_WT + SZ_CTXB);
  unsigned short* qb   = (unsigned short*)(ws + SZ_CTXB + SZ_XB + 4 * SZ_WT + 2 * SZ_CTXB);

  cvt_kernel<<<dim3(2048), dim3(256), 0, stream>>>(ctx, ctxb, NB * NKV * DIMF);
  cvt_kernel<<<dim3(1024), dim3(256), 0, stream>>>(x, xb, NB * NQ * DIMF);
  twt_kernel<<<dim3(24, 24, 4), dim3(32, 8), 0, stream>>>(Wk, Wv, Wq, Wo, wkt, wvt, wqt, wot);

  gemm_kernel<0><<<dim3(3072), dim3(256), 0, stream>>>(ctxb, wkt, kb, rope_k);
  gemm_kernel<1><<<dim3(3072), dim3(256), 0, stream>>>(ctxb, wvt, vtb, nullptr);
  gemm_kernel<2><<<dim3(32, 6), dim3(256), 0, stream>>>(xb, wqt, qb, rope_q);

  attn_kernel<<<dim3(768), dim3(256), 0, stream>>>(qb, kb, vtb, ob);

  gemm_kernel<3><<<dim3(32, 6), dim3(256), 0, stream>>>(ob, wot, d_out, nullptr);
}